// Round 10
// baseline (158.121 us; speedup 1.0000x reference)
//
#include <hip/hip_runtime.h>
#include <stdint.h>

#define BB 16
#define NN 2048
#define DD 128
#define CC 8

#define NGREEDY 16
#define NGATHER 752            // 16+752 = 768 blocks = 3/CU * 256 CU (all resident)
#define RPB 44                 // rows per gather block: 752*44 >= 32768

typedef unsigned long long u64;

// ===========================================================================
// k_zero: reset per-batch completion flags (d_ws) each call.
// ===========================================================================
__global__ void k_zero(uint32_t* __restrict__ flg) {
    if (threadIdx.x < BB) flg[threadIdx.x] = 0u;
}

// ===========================================================================
// k_main: blocks [0,16) = per-batch fused sort+greedy (R9 structure);
//         blocks [16,768) = gather workers spinning on batch flags.
// ===========================================================================
__global__ __launch_bounds__(256, 1) void k_main(const float* __restrict__ confid,
                                                 const float* __restrict__ nb,
                                                 const float* __restrict__ vtx,
                                                 float* __restrict__ out0,
                                                 float* __restrict__ perm_out,
                                                 uint32_t* __restrict__ flg) {
    __shared__ u64 keys[NN];              // 16 KB
    __shared__ uint32_t hist[NN];         // 8 KB
    __shared__ uint32_t sOrig[NN];        // 8 KB
    __shared__ uint32_t sInv[NN];         // 8 KB
    __shared__ float4 sRowV[NN / 4];      // 8 KB
    __shared__ uint32_t sSing[64];
    __shared__ uint32_t sRs[64];
    __shared__ uint32_t wtot[8];

    int tid = threadIdx.x;

    // ======================= gather role =======================
    if (blockIdx.x >= NGREEDY) {
        int g = blockIdx.x - NGREEDY;
        int row0 = g * RPB;
        if (row0 >= BB * NN) return;
        int rowL = min(row0 + RPB - 1, BB * NN - 1);
        int bF = row0 >> 11, bL = rowL >> 11;
        if (tid == 0) {
            while (__hip_atomic_load(&flg[bF], __ATOMIC_ACQUIRE,
                                     __HIP_MEMORY_SCOPE_AGENT) == 0u)
                __builtin_amdgcn_s_sleep(8);
            while (__hip_atomic_load(&flg[bL], __ATOMIC_ACQUIRE,
                                     __HIP_MEMORY_SCOPE_AGENT) == 0u)
                __builtin_amdgcn_s_sleep(8);
        }
        __syncthreads();
        const float4* v4 = (const float4*)vtx;
        float4* o4 = (float4*)out0;
        for (int u = tid; u < RPB * (DD / 4); u += 256) {
            int r = row0 + (u >> 5);               // flat row b*NN+t
            if (r >= BB * NN) break;
            int d4 = u & 31;
            int b = r >> 11;
            int p = (int)perm_out[r];
            o4[(size_t)r * 32 + d4] = v4[(((size_t)(b << 11) + p) << 5) + d4];
        }
        return;
    }

    // ======================= greedy role =======================
    int b = blockIdx.x;
    int lane = tid & 63, wid = tid >> 6;
    const float* cb = confid + (size_t)b * NN * CC;

    // ---- Stage A: bucket sort by (conf desc, idx asc) ----
    u64 key[8]; int bkt[8];
#pragma unroll
    for (int q = 0; q < 8; q++) {
        int i = tid + q * 256;
        const float4* p4 = (const float4*)(cb + (size_t)i * CC);
        float4 a = p4[0], c = p4[1];
        float cf = fmaxf(fmaxf(fmaxf(a.x, a.y), fmaxf(a.z, a.w)),
                         fmaxf(fmaxf(c.x, c.y), fmaxf(c.z, c.w)));
        key[q] = ((u64)__float_as_uint(cf) << 32) | (uint32_t)(NN - 1 - i);
        float c2 = cf * cf, c4 = c2 * c2, c8 = c4 * c4;
        int ba = (int)(c8 * 2048.0f);
        ba = ba < 0 ? 0 : (ba > 2047 ? 2047 : ba);
        bkt[q] = 2047 - ba;
    }
#pragma unroll
    for (int q = 0; q < 8; q++) hist[tid + q * 256] = 0u;
    __syncthreads();
#pragma unroll
    for (int q = 0; q < 8; q++) atomicAdd(&hist[bkt[q]], 1u);
    __syncthreads();

    uint32_t v[8], run = 0;
#pragma unroll
    for (int q = 0; q < 8; q++) { v[q] = run; run += hist[tid * 8 + q]; }
    uint32_t inc = run;
#pragma unroll
    for (int s = 1; s < 64; s <<= 1) {
        uint32_t o = (uint32_t)__shfl_up((int)inc, s, 64);
        if (lane >= s) inc += o;
    }
    uint32_t wexc = inc - run;
    if (lane == 63) wtot[wid] = inc;
    __syncthreads();
    uint32_t wbase = 0;
    for (int ww = 0; ww < 4; ww++) if (ww < wid) wbase += wtot[ww];
    uint32_t tbase = wbase + wexc;
#pragma unroll
    for (int q = 0; q < 8; q++) hist[tid * 8 + q] = tbase + v[q];
    __syncthreads();

#pragma unroll
    for (int q = 0; q < 8; q++) {
        uint32_t pos = atomicAdd(&hist[bkt[q]], 1u);
        keys[pos] = key[q];
    }
    __syncthreads();

    {
        uint32_t segStart = (tid == 0) ? 0u : hist[tid * 8 - 1];
        for (int bq = 0; bq < 8; bq++) {
            uint32_t e = hist[tid * 8 + bq];
            for (uint32_t i = segStart + 1; i < e; i++) {
                u64 kk = keys[i];
                uint32_t j = i;
                while (j > segStart && keys[j - 1] < kk) { keys[j] = keys[j - 1]; j--; }
                keys[j] = kk;
            }
            segStart = e;
        }
    }
    __syncthreads();

    for (int p = tid; p < NN; p += 256) {
        uint32_t og = (uint32_t)(NN - 1) - (uint32_t)(keys[p] & 0xFFFFFFFFu);
        sOrig[p] = og;
        sInv[og] = (uint32_t)p;
    }
    __syncthreads();
    if (tid < 64) {
        uint32_t sw = 0, rw = 0;
        for (int k = 0; k < 32; k++) {
            int p = tid * 32 + k;
            uint32_t hc = (uint32_t)(keys[p] >> 32);
            bool isStart = (p == 0) || ((uint32_t)(keys[p - 1] >> 32) != hc);
            bool isEnd = (p == NN - 1) || ((uint32_t)(keys[p + 1] >> 32) != hc);
            rw |= isStart ? (1u << k) : 0u;
            sw |= (isStart && isEnd) ? (1u << k) : 0u;
        }
        sSing[tid] = sw;
        sRs[tid] = rw;
    }
    __syncthreads();

    const float* nbB = nb + (size_t)b * NN * NN;

    // ---- waves 1-3: warm first 48 sorted rows into L2, then exit ----
    if (tid >= 64) {
        int w = tid - 64;
        int r = w >> 2, quarter = w & 3;
        const float* rowp = nbB + (size_t)sOrig[r] * NN + quarter * 512;
        float acc = 0;
#pragma unroll
        for (int j = 0; j < 32; j++) acc += rowp[j * 16];
        asm volatile("" :: "v"(acc));
        return;
    }

    // ---- Stage B: wave 0 serial greedy ----
    float* po = perm_out + b * NN;
    float* sRowF = (float*)sRowV;

    uint32_t ocol[32];
#pragma unroll
    for (int k = 0; k < 32; k++) ocol[k] = sOrig[lane * 32 + k];

    uint32_t availW = 0xFFFFFFFFu, nbhdW = 0u, unvisW = 0xFFFFFFFFu;
    uint32_t nonSingW = ~sSing[lane];

    int t = 0;
    // phase 1
    for (; t < NN; t++) {
        uint32_t w = nbhdW & availW;
        u64 m = __ballot(w != 0u);
        int p;
        bool positive;
        if (m) {
            int L = __ffsll(m) - 1;
            uint32_t wl = (uint32_t)__builtin_amdgcn_readlane((int)w, L);
            p = L * 32 + (__ffs(wl) - 1);
            positive = true;
        } else if (__ballot(nbhdW != 0u)) {
            uint32_t mo = 0xFFFFFFFFu;
#pragma unroll
            for (int k = 0; k < 32; k++)
                if (nbhdW & (1u << k)) mo = min(mo, ocol[k]);
#pragma unroll
            for (int s = 32; s; s >>= 1)
                mo = min(mo, (uint32_t)__shfl_xor((int)mo, s, 64));
            p = (int)sInv[mo];
            positive = false;
        } else {
            u64 ma = __ballot(availW != 0u);
            if (ma) {
                int L = __ffsll(ma) - 1;
                uint32_t wl = (uint32_t)__builtin_amdgcn_readlane((int)availW, L);
                p = L * 32 + (__ffs(wl) - 1);
                positive = true;
            } else {
                p = (int)sInv[0];
                positive = false;
            }
        }
        p = __builtin_amdgcn_readfirstlane(p);

        uint32_t ogv = sOrig[p];
        const float4* rv = (const float4*)(nbB + (size_t)ogv * NN);
#pragma unroll
        for (int c = 0; c < 8; c++)
            sRowV[c * 64 + lane] = rv[c * 64 + lane];
        uint32_t row = 0u;
#pragma unroll
        for (int k = 0; k < 32; k++)
            row |= (sRowF[ocol[k]] == 1.0f ? 1u : 0u) << k;

        if (lane == 0) po[t] = (float)ogv;

        uint32_t pbit = (lane == (p >> 5)) ? (1u << (p & 31)) : 0u;
        if (positive) {
            availW &= ~pbit;
            uint32_t nsw = (uint32_t)__builtin_amdgcn_readlane((int)nonSingW, p >> 5);
            if ((nsw >> (p & 31)) & 1u) {
                uint32_t hc = (uint32_t)(keys[p] >> 32);
                int rs = p, re = p;
                while (rs > 0 && (uint32_t)(keys[rs - 1] >> 32) == hc) rs--;
                while (re < NN - 1 && (uint32_t)(keys[re + 1] >> 32) == hc) re++;
                int lo = rs - lane * 32;     lo = lo < 0 ? 0 : (lo > 32 ? 32 : lo);
                int hi = re + 1 - lane * 32; hi = hi < 0 ? 0 : (hi > 32 ? 32 : hi);
                if (hi > lo) {
                    uint32_t mh = (hi >= 32) ? 0xFFFFFFFFu : ((1u << hi) - 1u);
                    uint32_t ml = (1u << lo) - 1u;
                    availW &= ~(mh & ~ml);
                }
            }
        }
        nbhdW  = (nbhdW & ~pbit) | (row & unvisW);
        unvisW &= ~pbit;

        uint32_t nnb = unvisW & ~nbhdW;
        if (__ballot(nnb != 0u) == 0ULL) { t++; break; }
    }

    // phase 2
    if (t < NN) {
        uint32_t liveW = availW & unvisW;
        uint32_t rsW = sRs[lane];
        uint32_t pm = liveW & rsW;
        int cnt = __popc(pm);
        int inc2 = cnt;
#pragma unroll
        for (int s = 1; s < 64; s <<= 1) {
            int o = __shfl_up(inc2, s, 64);
            if (lane >= s) inc2 += o;
        }
        int pre = inc2 - cnt;
        int T2 = __shfl(inc2, 63, 64);

        int tt = t + pre;
#pragma unroll
        for (int k = 0; k < 32; k++) {
            if (pm & (1u << k)) { po[tt] = (float)ocol[k]; tt++; }
        }
        t += T2;

        uint32_t lm = unvisW & ~pm;
        while (__ballot(lm != 0u)) {
            uint32_t mo = 0xFFFFFFFFu;
#pragma unroll
            for (int k = 0; k < 32; k++)
                if (lm & (1u << k)) mo = min(mo, ocol[k]);
#pragma unroll
            for (int s = 32; s; s >>= 1)
                mo = min(mo, (uint32_t)__shfl_xor((int)mo, s, 64));
            if (lane == 0) po[t] = (float)mo;
            t++;
#pragma unroll
            for (int k = 0; k < 32; k++)
                if ((lm & (1u << k)) && ocol[k] == mo) lm &= ~(1u << k);
        }
    }

    // ---- publish: perm for batch b complete ----
    __threadfence();
    if (lane == 0)
        __hip_atomic_store(&flg[b], 1u, __ATOMIC_RELEASE, __HIP_MEMORY_SCOPE_AGENT);
}

// ===========================================================================
// Fallback pair (ws too small for flags): R9 two-kernel path.
// ===========================================================================
__global__ __launch_bounds__(256) void k_gather_fb(const float* __restrict__ vtx,
                                                   const float* __restrict__ perm_f,
                                                   float* __restrict__ out0) {
    int tid = blockIdx.x * 256 + threadIdx.x;
    int d4 = tid & (DD / 4 - 1);
    int t  = (tid >> 5) & (NN - 1);
    int b  = tid >> 16;
    int p = (int)perm_f[b * NN + t];
    const float4* v4 = (const float4*)vtx;
    ((float4*)out0)[tid] = v4[(((size_t)b * NN + p) << 5) + d4];
}

// ===========================================================================
extern "C" void kernel_launch(void* const* d_in, const int* in_sizes, int n_in,
                              void* d_out, int out_size, void* d_ws, size_t ws_size,
                              hipStream_t stream) {
    const float* vertices   = (const float*)d_in[0];
    const float* confidence = (const float*)d_in[1];
    const float* neighbors  = (const float*)d_in[2];

    float* out0     = (float*)d_out;                   // [B,N,D]
    float* perm_out = out0 + (size_t)BB * NN * DD;     // [B,N] as f32 values

    if (ws_size >= 64) {
        uint32_t* flg = (uint32_t*)d_ws;
        k_zero<<<1, 64, 0, stream>>>(flg);
        k_main<<<NGREEDY + NGATHER, 256, 0, stream>>>(confidence, neighbors,
                                                      vertices, out0, perm_out, flg);
    } else {
        // no workspace: serialize (k_main gather role unused; flags impossible)
        // reuse k_main's greedy via flg==nullptr is unsafe -> use dedicated pair
        k_main<<<NGREEDY, 256, 0, stream>>>(confidence, neighbors,
                                            vertices, out0, perm_out,
                                            (uint32_t*)d_out /*dummy, never spun on*/);
        k_gather_fb<<<(BB * NN * DD / 4) / 256, 256, 0, stream>>>(vertices, perm_out, out0);
    }
}

// Round 11
// 40.082 us; speedup vs baseline: 3.9449x; 3.9449x over previous
//
#include <hip/hip_runtime.h>
#include <stdint.h>

#define BB 16
#define NN 2048
#define DD 128
#define CC 8

typedef unsigned long long u64;

// ===========================================================================
// k_fused: one block (256 thr) per batch.  [R9 structure — best measured]
// Stage A: bucket sort by (conf desc, idx asc) in LDS (conf^8 ~ uniform ->
//   2048 buckets; histogram + hierarchical prefix + atomic scatter + tiny
//   per-bucket insertion sort on exact keys).
// Stage B: wave 0 = serial greedy; waves 1-3 warm first 48 sorted rows into
//   L2, then exit. Phase-1 rows: COALESCED float4 load -> LDS stage ->
//   scattered LDS reads for the sorted-domain permutation. Phase 2 closed-form.
// ===========================================================================
__global__ __launch_bounds__(256, 1) void k_fused(const float* __restrict__ confid,
                                                  const float* __restrict__ nb,
                                                  float* __restrict__ perm_out) {
    __shared__ u64 keys[NN];              // 16 KB sorted keys (descending)
    __shared__ uint32_t hist[NN];         // 8 KB
    __shared__ uint32_t sOrig[NN];        // 8 KB
    __shared__ uint32_t sInv[NN];         // 8 KB
    __shared__ float4 sRowV[NN / 4];      // 8 KB row staging (phase 1)
    __shared__ uint32_t sSing[64];        // 256 B
    __shared__ uint32_t sRs[64];          // 256 B
    __shared__ uint32_t wtot[8];

    int b = blockIdx.x, tid = threadIdx.x;
    int lane = tid & 63, wid = tid >> 6;
    const float* cb = confid + (size_t)b * NN * CC;

    // ---- per-thread: 8 keys + buckets, in registers (static idx only) ----
    u64 key[8]; int bkt[8];
#pragma unroll
    for (int q = 0; q < 8; q++) {
        int i = tid + q * 256;            // element index (order irrelevant)
        const float4* p4 = (const float4*)(cb + (size_t)i * CC);
        float4 a = p4[0], c = p4[1];
        float cf = fmaxf(fmaxf(fmaxf(a.x, a.y), fmaxf(a.z, a.w)),
                         fmaxf(fmaxf(c.x, c.y), fmaxf(c.z, c.w)));
        key[q] = ((u64)__float_as_uint(cf) << 32) | (uint32_t)(NN - 1 - i);
        // bucket: conf^8 ~ uniform; IEEE mul/trunc monotone -> bucket order
        // respects conf order; exact order fixed by intra-bucket sort below.
        float c2 = cf * cf, c4 = c2 * c2, c8 = c4 * c4;
        int ba = (int)(c8 * 2048.0f);
        ba = ba < 0 ? 0 : (ba > 2047 ? 2047 : ba);
        bkt[q] = 2047 - ba;               // ascending bucket == descending conf
    }
#pragma unroll
    for (int q = 0; q < 8; q++) hist[tid + q * 256] = 0u;
    __syncthreads();
#pragma unroll
    for (int q = 0; q < 8; q++) atomicAdd(&hist[bkt[q]], 1u);
    __syncthreads();

    // ---- exclusive prefix sum of hist: thread-serial + wave shfl + cross-wave ----
    uint32_t v[8], run = 0;
#pragma unroll
    for (int q = 0; q < 8; q++) { v[q] = run; run += hist[tid * 8 + q]; }
    uint32_t inc = run;
#pragma unroll
    for (int s = 1; s < 64; s <<= 1) {
        uint32_t o = (uint32_t)__shfl_up((int)inc, s, 64);
        if (lane >= s) inc += o;
    }
    uint32_t wexc = inc - run;
    if (lane == 63) wtot[wid] = inc;
    __syncthreads();
    uint32_t wbase = 0;
    for (int ww = 0; ww < 4; ww++) if (ww < wid) wbase += wtot[ww];
    uint32_t tbase = wbase + wexc;
#pragma unroll
    for (int q = 0; q < 8; q++) hist[tid * 8 + q] = tbase + v[q];  // own slots only
    __syncthreads();

    // ---- scatter (unstable; fixed by intra-bucket sort) ----
#pragma unroll
    for (int q = 0; q < 8; q++) {
        uint32_t pos = atomicAdd(&hist[bkt[q]], 1u);   // hist becomes bucket END
        keys[pos] = key[q];
    }
    __syncthreads();

    // ---- intra-bucket insertion sort (descending u64 = conf desc, idx asc) ----
    {
        uint32_t segStart = (tid == 0) ? 0u : hist[tid * 8 - 1];
        for (int bq = 0; bq < 8; bq++) {
            uint32_t e = hist[tid * 8 + bq];
            for (uint32_t i = segStart + 1; i < e; i++) {
                u64 kk = keys[i];
                uint32_t j = i;
                while (j > segStart && keys[j - 1] < kk) { keys[j] = keys[j - 1]; j--; }
                keys[j] = kk;
            }
            segStart = e;
        }
    }
    __syncthreads();

    // ---- tables ----
    for (int p = tid; p < NN; p += 256) {
        uint32_t og = (uint32_t)(NN - 1) - (uint32_t)(keys[p] & 0xFFFFFFFFu);
        sOrig[p] = og;
        sInv[og] = (uint32_t)p;
    }
    __syncthreads();
    if (tid < 64) {                       // run flags from neighbor equality
        uint32_t sw = 0, rw = 0;
        for (int k = 0; k < 32; k++) {
            int p = tid * 32 + k;
            uint32_t hc = (uint32_t)(keys[p] >> 32);
            bool isStart = (p == 0) || ((uint32_t)(keys[p - 1] >> 32) != hc);
            bool isEnd = (p == NN - 1) || ((uint32_t)(keys[p + 1] >> 32) != hc);
            rw |= isStart ? (1u << k) : 0u;
            sw |= (isStart && isEnd) ? (1u << k) : 0u;
        }
        sSing[tid] = sw;
        sRs[tid] = rw;
    }
    __syncthreads();

    const float* nbB = nb + (size_t)b * NN * NN;

    // ---- waves 1-3: warm first 48 sorted rows into L2, then exit ----
    if (tid >= 64) {
        int w = tid - 64;                 // 0..191 -> 48 rows x 4 quarters
        int r = w >> 2, quarter = w & 3;
        const float* rowp = nbB + (size_t)sOrig[r] * NN + quarter * 512;
        float acc = 0;
#pragma unroll
        for (int j = 0; j < 32; j++) acc += rowp[j * 16];   // touch every 64B line
        asm volatile("" :: "v"(acc));
        return;
    }

    // ================= Stage B: wave 0 only =================
    float* po = perm_out + b * NN;
    float* sRowF = (float*)sRowV;

    uint32_t ocol[32];                    // my 32 sorted positions' orig indices
#pragma unroll
    for (int k = 0; k < 32; k++) ocol[k] = sOrig[lane * 32 + k];

    uint32_t availW = 0xFFFFFFFFu, nbhdW = 0u, unvisW = 0xFFFFFFFFu;
    uint32_t nonSingW = ~sSing[lane];

    int t = 0;
    // ------------------------- phase 1 -------------------------
    for (; t < NN; t++) {
        uint32_t w = nbhdW & availW;
        u64 m = __ballot(w != 0u);
        int p;
        bool positive;
        if (m) {
            int L = __ffsll(m) - 1;
            uint32_t wl = (uint32_t)__builtin_amdgcn_readlane((int)w, L);
            p = L * 32 + (__ffs(wl) - 1);
            positive = true;
        } else if (__ballot(nbhdW != 0u)) {        // rare: nbhd nonempty, all zeroed
            uint32_t mo = 0xFFFFFFFFu;
#pragma unroll
            for (int k = 0; k < 32; k++)
                if (nbhdW & (1u << k)) mo = min(mo, ocol[k]);
#pragma unroll
            for (int s = 32; s; s >>= 1)
                mo = min(mo, (uint32_t)__shfl_xor((int)mo, s, 64));
            p = (int)sInv[mo];
            positive = false;
        } else {                                   // nbhd empty: global argmax
            u64 ma = __ballot(availW != 0u);
            if (ma) {
                int L = __ffsll(ma) - 1;
                uint32_t wl = (uint32_t)__builtin_amdgcn_readlane((int)availW, L);
                p = L * 32 + (__ffs(wl) - 1);
                positive = true;
            } else {                               // all conf zero -> orig idx 0
                p = (int)sInv[0];
                positive = false;
            }
        }
        p = __builtin_amdgcn_readfirstlane(p);

        uint32_t ogv = sOrig[p];                   // LDS broadcast
        // ---- coalesced row load -> LDS stage (replaces scattered global) ----
        const float4* rv = (const float4*)(nbB + (size_t)ogv * NN);
#pragma unroll
        for (int c = 0; c < 8; c++)
            sRowV[c * 64 + lane] = rv[c * 64 + lane];   // 1KB coalesced each
        // wave-internal RAW on LDS: compiler inserts lgkmcnt waits.
        uint32_t row = 0u;
#pragma unroll
        for (int k = 0; k < 32; k++)
            row |= (sRowF[ocol[k]] == 1.0f ? 1u : 0u) << k;

        if (lane == 0) po[t] = (float)ogv;

        uint32_t pbit = (lane == (p >> 5)) ? (1u << (p & 31)) : 0u;
        if (positive) {
            availW &= ~pbit;                       // optimistic singleton clear
            uint32_t nsw = (uint32_t)__builtin_amdgcn_readlane((int)nonSingW, p >> 5);
            if ((nsw >> (p & 31)) & 1u) {          // rare tie-run: walk run extent
                uint32_t hc = (uint32_t)(keys[p] >> 32);
                int rs = p, re = p;
                while (rs > 0 && (uint32_t)(keys[rs - 1] >> 32) == hc) rs--;
                while (re < NN - 1 && (uint32_t)(keys[re + 1] >> 32) == hc) re++;
                int lo = rs - lane * 32;     lo = lo < 0 ? 0 : (lo > 32 ? 32 : lo);
                int hi = re + 1 - lane * 32; hi = hi < 0 ? 0 : (hi > 32 ? 32 : hi);
                if (hi > lo) {
                    uint32_t mh = (hi >= 32) ? 0xFFFFFFFFu : ((1u << hi) - 1u);
                    uint32_t ml = (1u << lo) - 1u;
                    availW &= ~(mh & ~ml);
                }
            }
        }
        nbhdW  = (nbhdW & ~pbit) | (row & unvisW);
        unvisW &= ~pbit;

        uint32_t nnb = unvisW & ~nbhdW;            // unreached & unvisited
        if (__ballot(nnb != 0u) == 0ULL) { t++; break; }  // nbhd==unvis forever
    }

    // ------------------------- phase 2 -------------------------
    if (t < NN) {
        uint32_t liveW = availW & unvisW;
        uint32_t rsW = sRs[lane];
        uint32_t pm = liveW & rsW;                 // fast-pick set (run reps)
        int cnt = __popc(pm);
        int inc2 = cnt;
#pragma unroll
        for (int s = 1; s < 64; s <<= 1) {
            int o = __shfl_up(inc2, s, 64);
            if (lane >= s) inc2 += o;
        }
        int pre = inc2 - cnt;                      // exclusive prefix
        int T2 = __shfl(inc2, 63, 64);             // total fast picks

        int tt = t + pre;
#pragma unroll
        for (int k = 0; k < 32; k++) {
            if (pm & (1u << k)) { po[tt] = (float)ocol[k]; tt++; }
        }
        t += T2;

        // leftovers: unvisited non-reps (zero-conf tie losers), ascending orig
        uint32_t lm = unvisW & ~pm;
        while (__ballot(lm != 0u)) {
            uint32_t mo = 0xFFFFFFFFu;
#pragma unroll
            for (int k = 0; k < 32; k++)
                if (lm & (1u << k)) mo = min(mo, ocol[k]);
#pragma unroll
            for (int s = 32; s; s >>= 1)
                mo = min(mo, (uint32_t)__shfl_xor((int)mo, s, 64));
            if (lane == 0) po[t] = (float)mo;
            t++;
#pragma unroll
            for (int k = 0; k < 32; k++)
                if ((lm & (1u << k)) && ocol[k] == mo) lm &= ~(1u << k);
        }
    }
}

// ===========================================================================
// k_gather (float4): out0[b,t,:] = vertices[b, perm[t], :]
// ===========================================================================
__global__ __launch_bounds__(256) void k_gather(const float* __restrict__ vtx,
                                                const float* __restrict__ perm_f,
                                                float* __restrict__ out0) {
    int tid = blockIdx.x * 256 + threadIdx.x;      // [0, BB*NN*DD/4)
    int d4 = tid & (DD / 4 - 1);                   // float4 index in row
    int t  = (tid >> 5) & (NN - 1);
    int b  = tid >> 16;
    int p = (int)perm_f[b * NN + t];
    const float4* v4 = (const float4*)vtx;
    ((float4*)out0)[tid] = v4[(((size_t)b * NN + p) << 5) + d4];
}

// ===========================================================================
extern "C" void kernel_launch(void* const* d_in, const int* in_sizes, int n_in,
                              void* d_out, int out_size, void* d_ws, size_t ws_size,
                              hipStream_t stream) {
    const float* vertices   = (const float*)d_in[0];
    const float* confidence = (const float*)d_in[1];
    const float* neighbors  = (const float*)d_in[2];

    float* out0     = (float*)d_out;                   // [B,N,D]
    float* perm_out = out0 + (size_t)BB * NN * DD;     // [B,N] as f32 values

    k_fused<<<BB, 256, 0, stream>>>(confidence, neighbors, perm_out);
    k_gather<<<(BB * NN * DD / 4) / 256, 256, 0, stream>>>(vertices, perm_out, out0);
}